// Round 1
// baseline (437.449 us; speedup 1.0000x reference)
//
#include <hip/hip_runtime.h>

#define C_ 2048
#define U_ 32
#define D_ 16
#define I_ 8
#define B_ 64

// xt[c][b][i] = x[b][i][c]   (write-coalesced transpose)
__global__ __launch_bounds__(256) void transpose_kernel(const float* __restrict__ x,
                                                        float* __restrict__ xt) {
    int idx = blockIdx.x * 256 + threadIdx.x;       // 0 .. C*B*I-1 = 1048575
    int i = idx & 7;
    int b = (idx >> 3) & 63;
    int c = idx >> 9;
    xt[idx] = x[(b * 8 + i) * 2048 + c];
}

// c_ij[c,u] = softmax over u of b_ij[c,u] ; one thread per c
__global__ __launch_bounds__(256) void softmax_kernel(const float* __restrict__ bij,
                                                      float* __restrict__ cij) {
    int c = blockIdx.x * 256 + threadIdx.x;         // grid = 8 -> 2048 threads
    float vals[32];
    float m = -1e30f;
#pragma unroll
    for (int u = 0; u < 32; ++u) { vals[u] = bij[c * 32 + u]; m = fmaxf(m, vals[u]); }
    float ssum = 0.f;
#pragma unroll
    for (int u = 0; u < 32; ++u) { vals[u] = expf(vals[u] - m); ssum += vals[u]; }
    float inv = 1.f / ssum;
#pragma unroll
    for (int u = 0; u < 32; ++u) cij[c * 32 + u] = vals[u] * inv;
}

// s[b,u,d] = sum_c c_ij[c,u] * sum_i W[c,u,d,i] * xt[c,b,i]
// grid.x = U * (B/4) = 32*16 = 512 ; block = 256 ; each block: one u, 4 b's
__global__ __launch_bounds__(256) void s_kernel(const float* __restrict__ xt,
                                                const float* __restrict__ W,
                                                const float* __restrict__ cij,
                                                float* __restrict__ s) {
    const int u  = blockIdx.x >> 4;
    const int b0 = (blockIdx.x & 15) * 4;
    const int t  = threadIdx.x;

    float acc[4][16];
#pragma unroll
    for (int bb = 0; bb < 4; ++bb)
#pragma unroll
        for (int d = 0; d < 16; ++d) acc[bb][d] = 0.f;

    for (int c = t; c < C_; c += 256) {
        float cw = cij[c * 32 + u];
        // xt[c][b0..b0+3][0..7] : 32 contiguous floats
        const float4* xp = reinterpret_cast<const float4*>(xt + (size_t)(c * 64 + b0) * 8);
        float4 xq[8];
#pragma unroll
        for (int q = 0; q < 8; ++q) xq[q] = xp[q];
        // W[c,u,:,:] : 128 contiguous floats
        const float4* Wp = reinterpret_cast<const float4*>(W + (size_t)(c * 32 + u) * 128);
#pragma unroll
        for (int d = 0; d < 16; ++d) {
            float4 w0 = Wp[2 * d], w1 = Wp[2 * d + 1];
#pragma unroll
            for (int bb = 0; bb < 4; ++bb) {
                const float4 a0 = xq[bb * 2], a1 = xq[bb * 2 + 1];
                float dot = w0.x * a0.x + w0.y * a0.y + w0.z * a0.z + w0.w * a0.w
                          + w1.x * a1.x + w1.y * a1.y + w1.z * a1.z + w1.w * a1.w;
                acc[bb][d] += cw * dot;
            }
        }
    }

    __shared__ float red[256][17];   // +1 pad breaks bank conflicts
#pragma unroll 1
    for (int bb = 0; bb < 4; ++bb) {
#pragma unroll
        for (int d = 0; d < 16; ++d) red[t][d] = acc[bb][d];
        __syncthreads();
        for (int str = 128; str >= 1; str >>= 1) {
            if (t < str) {
#pragma unroll
                for (int d = 0; d < 16; ++d) red[t][d] += red[t + str][d];
            }
            __syncthreads();
        }
        if (t < 16) s[((size_t)(b0 + bb) * 32 + u) * 16 + t] = red[0][t];
        __syncthreads();
    }
}

// squash: mag_sq over the U axis per (b,d) (faithful to reference quirk)
// v[b,u,d] = s * msq/((1+msq)*sqrt(msq)) ; writes v (ws) and out (d_out)
__global__ __launch_bounds__(256) void v_kernel(const float* __restrict__ s,
                                                float* __restrict__ v,
                                                float* __restrict__ out) {
    int n = blockIdx.x * 256 + threadIdx.x;         // grid = 4 -> 1024 = B*D
    int b = n >> 4, d = n & 15;
    float msq = 0.f;
#pragma unroll
    for (int u = 0; u < 32; ++u) {
        float sv = s[((size_t)b * 32 + u) * 16 + d];
        msq += sv * sv;
    }
    float scale = msq / ((1.f + msq) * sqrtf(msq));
#pragma unroll
    for (int u = 0; u < 32; ++u) {
        size_t idx = ((size_t)b * 32 + u) * 16 + d;
        float val = s[idx] * scale;
        v[idx] = val;
        out[idx] = val;
    }
}

// b_ij[c,u] += (1/B) * sum_{b,d} u_hat[b,c,u,d] * v[b,u,d]
// grid = C = 2048 ; block = 256 ; lane: u = t>>3, d-pair = (t&7)*2
__global__ __launch_bounds__(256) void delta_kernel(const float* __restrict__ xt,
                                                    const float* __restrict__ W,
                                                    const float* __restrict__ v,
                                                    float* __restrict__ bij) {
    const int c = blockIdx.x;
    const int t = threadIdx.x;
    const int u = t >> 3;
    const int d0 = (t & 7) * 2;

    __shared__ float xs[64][8];
    for (int k = t; k < 512; k += 256) xs[k >> 3][k & 7] = xt[(size_t)c * 512 + k];
    __syncthreads();

    const float4* Wp = reinterpret_cast<const float4*>(W + (size_t)(c * 32 + u) * 128 + d0 * 8);
    float4 w00 = Wp[0], w01 = Wp[1], w10 = Wp[2], w11 = Wp[3];

    float partial = 0.f;
#pragma unroll 4
    for (int b = 0; b < 64; ++b) {
        float x0 = xs[b][0], x1 = xs[b][1], x2 = xs[b][2], x3 = xs[b][3];
        float x4 = xs[b][4], x5 = xs[b][5], x6 = xs[b][6], x7 = xs[b][7];
        float uh0 = w00.x * x0 + w00.y * x1 + w00.z * x2 + w00.w * x3
                  + w01.x * x4 + w01.y * x5 + w01.z * x6 + w01.w * x7;
        float uh1 = w10.x * x0 + w10.y * x1 + w10.z * x2 + w10.w * x3
                  + w11.x * x4 + w11.y * x5 + w11.z * x6 + w11.w * x7;
        const float2 vv = *reinterpret_cast<const float2*>(v + ((size_t)(b * 32 + u) * 16 + d0));
        partial += uh0 * vv.x + uh1 * vv.y;
    }
    // reduce over the 8 consecutive lanes sharing u
    partial += __shfl_xor(partial, 1);
    partial += __shfl_xor(partial, 2);
    partial += __shfl_xor(partial, 4);
    if ((t & 7) == 0) bij[c * 32 + u] += partial * (1.0f / 64.0f);
}

extern "C" void kernel_launch(void* const* d_in, const int* in_sizes, int n_in,
                              void* d_out, int out_size, void* d_ws, size_t ws_size,
                              hipStream_t stream) {
    const float* x = (const float*)d_in[0];   // (B, I, C) = (64, 8, 2048)
    const float* W = (const float*)d_in[1];   // (C, U, D, I) = (2048, 32, 16, 8)
    float* out = (float*)d_out;               // (B, U, D, 1) flat = 32768 fp32

    float* ws  = (float*)d_ws;
    float* xt  = ws;                  // C*B*I   = 1,048,576 floats
    float* bij = xt + 1048576;        // C*U     = 65,536
    float* cij = bij + 65536;         // C*U     = 65,536
    float* s   = cij + 65536;         // B*U*D   = 32,768
    float* v   = s + 32768;           // B*U*D   = 32,768

    hipMemsetAsync(bij, 0, 65536 * sizeof(float), stream);
    transpose_kernel<<<4096, 256, 0, stream>>>(x, xt);

    for (int it = 0; it < 3; ++it) {
        softmax_kernel<<<8, 256, 0, stream>>>(bij, cij);
        s_kernel<<<512, 256, 0, stream>>>(xt, W, cij, s);
        v_kernel<<<4, 256, 0, stream>>>(s, v, out);
        if (it < 2) delta_kernel<<<2048, 256, 0, stream>>>(xt, W, v, bij);
    }
}

// Round 2
// 238.000 us; speedup vs baseline: 1.8380x; 1.8380x over previous
//
#include <hip/hip_runtime.h>

#define CC 64            // c per chunk in s-pass
#define NCHUNK 32        // 2048 / CC
#define SLAB 16          // c per LDS slab

// xt2[c][i][b] = x[b][i][c]  (reads coalesced, scattered writes absorbed by L2)
__global__ __launch_bounds__(256) void transpose_kernel(const float* __restrict__ x,
                                                        float* __restrict__ xt2) {
    int idx = blockIdx.x * 256 + threadIdx.x;       // input-linear (b,i,c)
    int c = idx & 2047;
    int bi = idx >> 11;                              // b*8 + i
    int b = bi >> 3, i = bi & 7;
    xt2[(size_t)c * 512 + i * 64 + b] = x[idx];
}

// c_ij[c,u] = softmax over u of b_ij[c,u] ; one thread per c
__global__ __launch_bounds__(256) void softmax_kernel(const float* __restrict__ bij,
                                                      float* __restrict__ cij) {
    int c = blockIdx.x * 256 + threadIdx.x;          // grid = 8
    float vals[32];
    float m = -1e30f;
#pragma unroll
    for (int u = 0; u < 32; ++u) { vals[u] = bij[c * 32 + u]; m = fmaxf(m, vals[u]); }
    float ssum = 0.f;
#pragma unroll
    for (int u = 0; u < 32; ++u) { vals[u] = expf(vals[u] - m); ssum += vals[u]; }
    float inv = 1.f / ssum;
#pragma unroll
    for (int u = 0; u < 32; ++u) cij[c * 32 + u] = vals[u] * inv;
}

// s-pass: part[chunk][u][d][b] = sum_{c in chunk} cij[c,u] * sum_i W[c,u,d,i]*x[b,i,c]
// grid = 32 u * 32 chunks = 1024 blocks; block 256 = 4 waves, all same u.
// lane: d0 = (l>>4)*4 (4 d's), b0 = (l&15)*4 (4 b's) -> 16 acc.
// W read direct from global: 16-lane groups broadcast the same 64B lines.
// x read from LDS [cl][i][b]: b128 at 16B lane stride (2-way bank = free).
__global__ __launch_bounds__(256, 4) void s_kernel2(const float* __restrict__ xt2,
                                                    const float* __restrict__ W,
                                                    const float* __restrict__ cij,
                                                    float* __restrict__ part) {
    const int u     = blockIdx.x >> 5;
    const int chunk = blockIdx.x & 31;
    const int t = threadIdx.x;
    const int w = t >> 6;
    const int l = t & 63;
    const int d0 = (l >> 4) * 4;
    const int b0 = (l & 15) * 4;

    __shared__ float lds[SLAB * 512];    // 32 KB; reused for cross-wave reduce

    float acc[16];
#pragma unroll
    for (int j = 0; j < 16; ++j) acc[j] = 0.f;

    const int cbase = chunk * CC;
    for (int slab = 0; slab < CC / SLAB; ++slab) {
        __syncthreads();
        const float4* src = reinterpret_cast<const float4*>(xt2 + (size_t)(cbase + slab * SLAB) * 512);
        float4* dst = reinterpret_cast<float4*>(lds);
#pragma unroll
        for (int k = 0; k < 8; ++k) dst[t + k * 256] = src[t + k * 256];
        __syncthreads();

#pragma unroll 1
        for (int j = 0; j < 4; ++j) {
            const int cl = w * 4 + j;
            const int c  = cbase + slab * SLAB + cl;
            const float cw = cij[c * 32 + u];
            // W row slice for this thread's 4 d's: 32 contiguous floats
            const float4* Wp = reinterpret_cast<const float4*>(W + (size_t)(c * 32 + u) * 128 + d0 * 8);
            float wv[32];
#pragma unroll
            for (int q = 0; q < 8; ++q) {
                float4 f = Wp[q];
                wv[q * 4 + 0] = f.x * cw;
                wv[q * 4 + 1] = f.y * cw;
                wv[q * 4 + 2] = f.z * cw;
                wv[q * 4 + 3] = f.w * cw;
            }
#pragma unroll
            for (int i = 0; i < 8; ++i) {
                float4 xv = *reinterpret_cast<const float4*>(lds + cl * 512 + i * 64 + b0);
#pragma unroll
                for (int dd = 0; dd < 4; ++dd) {
                    float wq = wv[dd * 8 + i];
                    acc[dd * 4 + 0] += wq * xv.x;
                    acc[dd * 4 + 1] += wq * xv.y;
                    acc[dd * 4 + 2] += wq * xv.z;
                    acc[dd * 4 + 3] += wq * xv.w;
                }
            }
        }
    }

    // cross-wave reduce in LDS (stride 17 floats: conflict-free scalar access)
    __syncthreads();
#pragma unroll
    for (int j = 0; j < 16; ++j) lds[(w * 64 + l) * 17 + j] = acc[j];
    __syncthreads();

    // thread t: lane l2 = t&63, dd = t>>6 ; sum 4 waves, write float4 over bi
    const int l2 = t & 63;
    const int dd = t >> 6;
    const int d0w = (l2 >> 4) * 4;
    const int b0w = (l2 & 15) * 4;
    float4 o;
    float* op = &o.x;
#pragma unroll
    for (int bi = 0; bi < 4; ++bi) {
        float a = 0.f;
#pragma unroll
        for (int ww = 0; ww < 4; ++ww) a += lds[(ww * 64 + l2) * 17 + dd * 4 + bi];
        op[bi] = a;
    }
    *reinterpret_cast<float4*>(part + ((size_t)(chunk * 32 + u) * 16 + d0w + dd) * 64 + b0w) = o;
}

// s[u][d][b] = sum_chunk part[chunk][u][d][b]
__global__ __launch_bounds__(256) void reduce_kernel(const float* __restrict__ part,
                                                     float* __restrict__ s) {
    int n = blockIdx.x * 256 + threadIdx.x;         // grid = 128 -> 32768
    float a = 0.f;
#pragma unroll
    for (int k = 0; k < 32; ++k) a += part[k * 32768 + n];
    s[n] = a;
}

// squash over the U axis per (b,d) (reference quirk), s layout [u][d][b]
__global__ __launch_bounds__(256) void v_kernel2(const float* __restrict__ s,
                                                 float* __restrict__ v,
                                                 float* __restrict__ out) {
    int n = blockIdx.x * 256 + threadIdx.x;         // grid = 4 -> 1024 = B*D
    int b = n >> 4, d = n & 15;
    float sv[32];
    float msq = 0.f;
#pragma unroll
    for (int u = 0; u < 32; ++u) {
        sv[u] = s[(u * 16 + d) * 64 + b];
        msq += sv[u] * sv[u];
    }
    float scale = msq / ((1.f + msq) * sqrtf(msq));
#pragma unroll
    for (int u = 0; u < 32; ++u) {
        float val = sv[u] * scale;
        v[(b * 32 + u) * 16 + d] = val;
        out[(b * 32 + u) * 16 + d] = val;
    }
}

// b_ij[c,u] += (1/B) * sum_{b,d} u_hat[b,c,u,d] * v[b,u,d]
// grid = C = 2048 ; block = 256 ; lane: u = t>>3, d-pair = (t&7)*2
__global__ __launch_bounds__(256) void delta_kernel(const float* __restrict__ xt2,
                                                    const float* __restrict__ W,
                                                    const float* __restrict__ v,
                                                    float* __restrict__ bij) {
    const int c = blockIdx.x;
    const int t = threadIdx.x;
    const int u = t >> 3;
    const int d0 = (t & 7) * 2;

    __shared__ float xs[512];            // [b][i] layout for vectorized reads
    for (int k = t; k < 512; k += 256) {
        // xt2 row is [i][b]: k = i*64+b -> store at b*8+i
        xs[(k & 63) * 8 + (k >> 6)] = xt2[(size_t)c * 512 + k];
    }
    __syncthreads();

    const float4* Wp = reinterpret_cast<const float4*>(W + (size_t)(c * 32 + u) * 128 + d0 * 8);
    float4 w00 = Wp[0], w01 = Wp[1], w10 = Wp[2], w11 = Wp[3];

    float partial = 0.f;
#pragma unroll 4
    for (int b = 0; b < 64; ++b) {
        const float4 xa = *reinterpret_cast<const float4*>(&xs[b * 8]);
        const float4 xb = *reinterpret_cast<const float4*>(&xs[b * 8 + 4]);
        float uh0 = w00.x * xa.x + w00.y * xa.y + w00.z * xa.z + w00.w * xa.w
                  + w01.x * xb.x + w01.y * xb.y + w01.z * xb.z + w01.w * xb.w;
        float uh1 = w10.x * xa.x + w10.y * xa.y + w10.z * xa.z + w10.w * xa.w
                  + w11.x * xb.x + w11.y * xb.y + w11.z * xb.z + w11.w * xb.w;
        const float2 vv = *reinterpret_cast<const float2*>(v + ((size_t)(b * 32 + u) * 16 + d0));
        partial += uh0 * vv.x + uh1 * vv.y;
    }
    partial += __shfl_xor(partial, 1);
    partial += __shfl_xor(partial, 2);
    partial += __shfl_xor(partial, 4);
    if ((t & 7) == 0) bij[c * 32 + u] += partial * (1.0f / 64.0f);
}

extern "C" void kernel_launch(void* const* d_in, const int* in_sizes, int n_in,
                              void* d_out, int out_size, void* d_ws, size_t ws_size,
                              hipStream_t stream) {
    const float* x = (const float*)d_in[0];   // (B, I, C) = (64, 8, 2048)
    const float* W = (const float*)d_in[1];   // (C, U, D, I) = (2048, 32, 16, 8)
    float* out = (float*)d_out;               // (B, U, D, 1) flat = 32768 fp32

    float* ws   = (float*)d_ws;
    float* xt2  = ws;                   // C*I*B    = 1,048,576 floats
    float* bij  = xt2 + 1048576;        // C*U      = 65,536
    float* cij  = bij + 65536;          // C*U      = 65,536
    float* s    = cij + 65536;          // U*D*B    = 32,768
    float* v    = s + 32768;            // B*U*D    = 32,768
    float* part = v + 32768;            // 32*U*D*B = 1,048,576

    hipMemsetAsync(bij, 0, 65536 * sizeof(float), stream);
    transpose_kernel<<<4096, 256, 0, stream>>>(x, xt2);

    for (int it = 0; it < 3; ++it) {
        softmax_kernel<<<8, 256, 0, stream>>>(bij, cij);
        s_kernel2<<<1024, 256, 0, stream>>>(xt2, W, cij, part);
        reduce_kernel<<<128, 256, 0, stream>>>(part, s);
        v_kernel2<<<4, 256, 0, stream>>>(s, v, out);
        if (it < 2) delta_kernel<<<2048, 256, 0, stream>>>(xt2, W, v, bij);
    }
}